// Round 1
// baseline (1031.643 us; speedup 1.0000x reference)
//
#include <hip/hip_runtime.h>

typedef unsigned short u16;
typedef unsigned int u32;
typedef __attribute__((ext_vector_type(8))) __bf16 bf16x8;
typedef __attribute__((ext_vector_type(4))) float f32x4;

// ---------- helpers ----------
__device__ __forceinline__ void gl_lds16(const void* g, void* l) {
  // async global->LDS, 16B per lane; LDS dest = wave-uniform base + lane*16
  __builtin_amdgcn_global_load_lds((__attribute__((address_space(1))) void*)g,
                                   (__attribute__((address_space(3))) void*)l,
                                   16, 0, 0);
}

__device__ __forceinline__ u16 f2bf(float f) {
  // RNE float->bf16 (inputs are finite; NaN not handled)
  u32 x = __builtin_bit_cast(u32, f);
  return (u16)((x + 0x7fffu + ((x >> 16) & 1u)) >> 16);
}

// ---------- fp32 -> bf16 convert (8 elems/thread) ----------
__global__ __launch_bounds__(256) void cvt_bf16(const float* __restrict__ in,
                                                u16* __restrict__ out, int n) {
  int i = (blockIdx.x * 256 + threadIdx.x) * 8;
  if (i >= n) return;
  const float4* p = (const float4*)(in + i);
  float4 a = p[0], b = p[1];
  uint4 u;
  u.x = f2bf(a.x) | ((u32)f2bf(a.y) << 16);
  u.y = f2bf(a.z) | ((u32)f2bf(a.w) << 16);
  u.z = f2bf(b.x) | ((u32)f2bf(b.y) << 16);
  u.w = f2bf(b.z) | ((u32)f2bf(b.w) << 16);
  *(uint4*)(out + i) = u;
}

// ---------- 2048x2048 transpose per batch (V -> V^T per head) ----------
__global__ __launch_bounds__(256) void transpose_2048(const u16* __restrict__ in,
                                                      u16* __restrict__ out) {
  __shared__ u16 tile[32][33];
  const size_t base = (size_t)blockIdx.z * 2048 * 2048;
  int x = blockIdx.x * 32 + threadIdx.x;
  int y = blockIdx.y * 32 + threadIdx.y;
  for (int j = 0; j < 32; j += 8)
    tile[threadIdx.y + j][threadIdx.x] = in[base + (size_t)(y + j) * 2048 + x];
  __syncthreads();
  x = blockIdx.y * 32 + threadIdx.x;
  y = blockIdx.x * 32 + threadIdx.y;
  for (int j = 0; j < 32; j += 8)
    out[base + (size_t)(y + j) * 2048 + x] = tile[threadIdx.x][threadIdx.y + j];
}

// ---------- C = A * B^T  (A:[M,K] bf16, B:[N,K] bf16, C fp32 or bf16) ----------
// 128x128 tile, BK=32, 4 waves (2x2 of 64x64), XOR-swizzled LDS (chunk ^ ((row>>1)&3))
template <bool F32OUT>
__global__ __launch_bounds__(256, 2)
void gemm_bt(const u16* __restrict__ A, const u16* __restrict__ B,
             void* __restrict__ Cptr, int M, int N, int K) {
  __shared__ u16 As[128 * 32];
  __shared__ u16 Bs[128 * 32];
  const int tid = threadIdx.x;
  const int lane = tid & 63, w = tid >> 6;
  const int m0 = blockIdx.y * 128, n0 = blockIdx.x * 128;
  const int wm = (w & 1) * 64, wn = (w >> 1) * 64;
  const int fm = lane & 15, quad = lane >> 4;
  const int sr = lane >> 2, sc = lane & 3;  // staging: row within 16-row issue, chunk pos
  f32x4 acc[4][4] = {};
  for (int k0 = 0; k0 < K; k0 += 32) {
    __syncthreads();
    for (int i = w; i < 8; i += 4) {
      int r = i * 16 + sr;
      int ca = sc ^ ((r >> 1) & 3);  // swizzle: position sc holds chunk ca
      gl_lds16(A + (size_t)(m0 + r) * K + k0 + ca * 8, &As[i * 512]);
      gl_lds16(B + (size_t)(n0 + r) * K + k0 + ca * 8, &Bs[i * 512]);
    }
    __syncthreads();
    bf16x8 af[4], bfr[4];
#pragma unroll
    for (int t = 0; t < 4; t++) {
      int ra = wm + t * 16 + fm;
      af[t] = *(const bf16x8*)&As[ra * 32 + ((quad ^ ((ra >> 1) & 3)) << 3)];
      int rb = wn + t * 16 + fm;
      bfr[t] = *(const bf16x8*)&Bs[rb * 32 + ((quad ^ ((rb >> 1) & 3)) << 3)];
    }
#pragma unroll
    for (int mt = 0; mt < 4; mt++)
#pragma unroll
      for (int nt = 0; nt < 4; nt++)
        acc[mt][nt] = __builtin_amdgcn_mfma_f32_16x16x32_bf16(af[mt], bfr[nt], acc[mt][nt], 0, 0, 0);
  }
  const int er = quad * 4;
#pragma unroll
  for (int mt = 0; mt < 4; mt++)
#pragma unroll
    for (int nt = 0; nt < 4; nt++)
#pragma unroll
      for (int r = 0; r < 4; r++) {
        size_t idx = (size_t)(m0 + wm + mt * 16 + er + r) * N + (n0 + wn + nt * 16 + fm);
        if (F32OUT) ((float*)Cptr)[idx] = acc[mt][nt][r];
        else        ((u16*)Cptr)[idx] = f2bf(acc[mt][nt][r]);
      }
}

// ---------- attention: per-64-key-block softmax, block outputs summed ----------
// grid (qt=16, h=16, b=2), 256 threads; wave w owns q-rows [w*32, w*32+32)
__global__ __launch_bounds__(256, 2)
void attn_kernel(const u16* __restrict__ Q, const u16* __restrict__ Kmat,
                 const u16* __restrict__ Vt, float* __restrict__ attn_out,
                 u16* __restrict__ ctx) {
  __shared__ u16 Ks[64 * 128];   // [key][hd], 16B-chunk pos = c ^ (key&15)
  __shared__ u16 Vts[128 * 64];  // [dd][key], chunk pos = c ^ (dd&7)
  __shared__ u16 Ps[128 * 64];   // [qrow][key], chunk pos = c ^ (row&7); wave-private rows
  const int tid = threadIdx.x, lane = tid & 63, w = tid >> 6;
  const int qt = blockIdx.x, h = blockIdx.y, b = blockIdx.z;
  const int q0 = qt * 128;
  const int fm = lane & 15, quad = lane >> 4;
  const float inv_scale = 0.08838834764831845f;  // 1/sqrt(128)

  // Q fragments in registers (one-time scattered 16B global reads)
  bf16x8 qf[2][4];
  {
    const u16* Qg = Q + (size_t)(b * 2048 + q0 + w * 32 + fm) * 2048 + h * 128;
#pragma unroll
    for (int mt = 0; mt < 2; mt++)
#pragma unroll
      for (int kt = 0; kt < 4; kt++)
        qf[mt][kt] = *(const bf16x8*)(Qg + (size_t)mt * 16 * 2048 + kt * 32 + quad * 8);
  }
  f32x4 cacc[2][8] = {};  // ctx accumulator, persists across all 32 k-blocks
  const u16* Kg = Kmat + (size_t)b * 2048 * 2048 + h * 128;
  const u16* Vg = Vt + (size_t)(b * 16 + h) * 128 * 2048;
  const int krl = lane >> 4, kcl = lane & 15;  // K staging: 4 rows x 16 chunks / issue
  const int vrl = lane >> 3, vcl = lane & 7;   // V staging: 8 rows x 8 chunks / issue

  for (int kb = 0; kb < 32; kb++) {
    __syncthreads();
    for (int i = w; i < 16; i += 4) {
      int rk = i * 4 + krl;
      int ck = kcl ^ (rk & 15);
      gl_lds16(Kg + (size_t)(kb * 64 + rk) * 2048 + ck * 8, &Ks[i * 512]);
      int rv = i * 8 + vrl;
      int cv = vcl ^ (rv & 7);
      gl_lds16(Vg + (size_t)rv * 2048 + kb * 64 + cv * 8, &Vts[i * 512]);
    }
    __syncthreads();

    // S = Q K^T  (this wave: 32 q-rows x 64 keys)
    f32x4 sacc[2][4] = {};
#pragma unroll
    for (int kt = 0; kt < 4; kt++) {
      bf16x8 kf[4];
#pragma unroll
      for (int nt = 0; nt < 4; nt++) {
        int rk = nt * 16 + fm;
        int ck = (kt * 4 + quad) ^ (rk & 15);
        kf[nt] = *(const bf16x8*)&Ks[rk * 128 + ck * 8];
      }
#pragma unroll
      for (int mt = 0; mt < 2; mt++)
#pragma unroll
        for (int nt = 0; nt < 4; nt++)
          sacc[mt][nt] = __builtin_amdgcn_mfma_f32_16x16x32_bf16(qf[mt][kt], kf[nt], sacc[mt][nt], 0, 0, 0);
    }

    // per-row softmax over this 64-key block; write fp32 probs + bf16 P tile
#pragma unroll
    for (int mt = 0; mt < 2; mt++)
#pragma unroll
      for (int r = 0; r < 4; r++) {
        float v0 = sacc[mt][0][r], v1 = sacc[mt][1][r], v2 = sacc[mt][2][r], v3 = sacc[mt][3][r];
        float mx = fmaxf(fmaxf(v0, v1), fmaxf(v2, v3));
        mx = fmaxf(mx, __shfl_xor(mx, 1));
        mx = fmaxf(mx, __shfl_xor(mx, 2));
        mx = fmaxf(mx, __shfl_xor(mx, 4));
        mx = fmaxf(mx, __shfl_xor(mx, 8));
        float e0 = __expf((v0 - mx) * inv_scale);
        float e1 = __expf((v1 - mx) * inv_scale);
        float e2 = __expf((v2 - mx) * inv_scale);
        float e3 = __expf((v3 - mx) * inv_scale);
        float s = e0 + e1 + e2 + e3;
        s += __shfl_xor(s, 1);
        s += __shfl_xor(s, 2);
        s += __shfl_xor(s, 4);
        s += __shfl_xor(s, 8);
        float inv = 1.0f / s;
        float p0 = e0 * inv, p1 = e1 * inv, p2 = e2 * inv, p3 = e3 * inv;
        int row = w * 32 + mt * 16 + quad * 4 + r;
        size_t ob = ((size_t)((b * 16 + h) * 2048 + q0 + row)) * 2048 + kb * 64;
        attn_out[ob + fm] = p0;
        attn_out[ob + 16 + fm] = p1;
        attn_out[ob + 32 + fm] = p2;
        attn_out[ob + 48 + fm] = p3;
        int rw7 = row & 7, fh = fm >> 3, fl = fm & 7;
        u16* pp = &Ps[row * 64];
        pp[(((0 + fh) ^ rw7) << 3) + fl] = f2bf(p0);
        pp[(((2 + fh) ^ rw7) << 3) + fl] = f2bf(p1);
        pp[(((4 + fh) ^ rw7) << 3) + fl] = f2bf(p2);
        pp[(((6 + fh) ^ rw7) << 3) + fl] = f2bf(p3);
      }

    // ctx += P * V   (Ps rows are wave-private: no barrier needed)
#pragma unroll
    for (int kt = 0; kt < 2; kt++) {
      bf16x8 pa[2], vb[8];
#pragma unroll
      for (int mt = 0; mt < 2; mt++) {
        int rp = w * 32 + mt * 16 + fm;
        int cp = (kt * 4 + quad) ^ (rp & 7);
        pa[mt] = *(const bf16x8*)&Ps[rp * 64 + cp * 8];
      }
#pragma unroll
      for (int nt = 0; nt < 8; nt++) {
        int rv = nt * 16 + fm;
        int cv = (kt * 4 + quad) ^ (rv & 7);
        vb[nt] = *(const bf16x8*)&Vts[rv * 64 + cv * 8];
      }
#pragma unroll
      for (int mt = 0; mt < 2; mt++)
#pragma unroll
        for (int nt = 0; nt < 8; nt++)
          cacc[mt][nt] = __builtin_amdgcn_mfma_f32_16x16x32_bf16(pa[mt], vb[nt], cacc[mt][nt], 0, 0, 0);
    }
  }

  // ctx [B,S,D] layout (= transpose(0,2,1,3).reshape fused)
#pragma unroll
  for (int mt = 0; mt < 2; mt++)
#pragma unroll
    for (int nt = 0; nt < 8; nt++)
#pragma unroll
      for (int r = 0; r < 4; r++) {
        int row = q0 + w * 32 + mt * 16 + quad * 4 + r;
        int col = h * 128 + nt * 16 + fm;
        ctx[(size_t)(b * 2048 + row) * 2048 + col] = f2bf(cacc[mt][nt][r]);
      }
}

extern "C" void kernel_launch(void* const* d_in, const int* in_sizes, int n_in,
                              void* d_out, int out_size, void* d_ws, size_t ws_size,
                              hipStream_t stream) {
  const float* query = (const float*)d_in[0];
  const float* key   = (const float*)d_in[1];
  const float* value = (const float*)d_in[2];
  const float* Wq = (const float*)d_in[3];
  const float* Wk = (const float*)d_in[4];
  const float* Wv = (const float*)d_in[5];
  const float* Wo = (const float*)d_in[6];
  // d_in[7] = block_size (fixed 64)

  float* out  = (float*)d_out;
  float* attn = out + (size_t)8388608;  // [B,H,S,S] region

  // workspace (bf16, 112 MiB total)
  u16* ws  = (u16*)d_ws;
  u16* wqb = ws;
  u16* wkb = wqb + 4194304;
  u16* wvb = wkb + 4194304;
  u16* wob = wvb + 4194304;
  u16* Qb  = wob + 4194304;
  u16* Kb  = Qb + 8388608;
  u16* Vb  = Kb + 8388608;
  u16* Vtb = Vb + 8388608;
  u16* ctx = Vtb + 8388608;
  // bf16 input copies live in the attn-weights region (dead before attn writes it)
  u16* Xq = (u16*)attn;
  u16* Xk = Xq + 8388608;
  u16* Xv = Xk + 8388608;

  cvt_bf16<<<4096, 256, 0, stream>>>(query, Xq, 8388608);
  cvt_bf16<<<4096, 256, 0, stream>>>(key,   Xk, 8388608);
  cvt_bf16<<<4096, 256, 0, stream>>>(value, Xv, 8388608);
  cvt_bf16<<<2048, 256, 0, stream>>>(Wq, wqb, 4194304);
  cvt_bf16<<<2048, 256, 0, stream>>>(Wk, wkb, 4194304);
  cvt_bf16<<<2048, 256, 0, stream>>>(Wv, wvb, 4194304);
  cvt_bf16<<<2048, 256, 0, stream>>>(Wo, wob, 4194304);

  dim3 gg(16, 32, 1);
  gemm_bt<false><<<gg, 256, 0, stream>>>(Xq, wqb, Qb, 4096, 2048, 2048);
  gemm_bt<false><<<gg, 256, 0, stream>>>(Xk, wkb, Kb, 4096, 2048, 2048);
  gemm_bt<false><<<gg, 256, 0, stream>>>(Xv, wvb, Vb, 4096, 2048, 2048);

  transpose_2048<<<dim3(64, 64, 2), dim3(32, 8), 0, stream>>>(Vb, Vtb);

  attn_kernel<<<dim3(16, 16, 2), 256, 0, stream>>>(Qb, Kb, Vtb, attn, ctx);

  gemm_bt<true><<<gg, 256, 0, stream>>>(ctx, wob, out, 4096, 2048, 2048);
}